// Round 9
// baseline (26.951 us; speedup 1.0000x reference)
//
#include <hip/hip_runtime.h>

#define NCH 64
#define WW  97

typedef float        f32x4 __attribute__((ext_vector_type(4)));
typedef unsigned int u32x4v __attribute__((ext_vector_type(4)));
typedef _Float16     h16x4 __attribute__((ext_vector_type(4)));
typedef unsigned int u32;

// Rotation-orbit representatives of (i,j,k) in [0,4)^3 under (i,j,k)->(j,k,i).
// First 4 are the diagonal (1-cube) orbits; remaining 20 are 3-cube orbits.
__constant__ unsigned char ORBITS[24] = {
  0x00, 0x15, 0x2A, 0x3F,                  // (0,0,0) (1,1,1) (2,2,2) (3,3,3)
  0x01, 0x02, 0x03, 0x05, 0x0A, 0x0F,      // (0,0,1)(0,0,2)(0,0,3)(0,1,1)(0,2,2)(0,3,3)
  0x06, 0x09, 0x07, 0x0D, 0x0B, 0x0E,      // (0,1,2)(0,2,1)(0,1,3)(0,3,1)(0,2,3)(0,3,2)
  0x16, 0x17, 0x1A, 0x1F, 0x2B, 0x2F,      // (1,1,2)(1,1,3)(1,2,2)(1,3,3)(2,2,3)(2,3,3)
  0x1B, 0x1E                               // (1,2,3)(1,3,2)
};

// Within batch b, x position = (row, tile, off): x[b][row][64*tile + off].
// Output (c,t,u) = own x at (c,t,u); weight-id from x at (t,u,c).
// WG owns orbit {(A,B,C),(B,C,A),(C,A,B)}: x read EXACTLY once from global.
__global__ __launch_bounds__(256)
void pw_kernel(const float* __restrict__ x,
               const float* __restrict__ w,
               float* __restrict__ out) {
  __shared__ h16x4 wexp[NCH * 32];                        // 16 KB monomial f16 coeffs
  __shared__ __align__(16) unsigned char sid[3][16 * 272]; // ids, row stride 272 (bank-spread)

  const int b    = blockIdx.y;
  const int ob   = ORBITS[blockIdx.x];
  const int nreg = (blockIdx.x < 4) ? 1 : 3;
  const int e0 = ((ob >> 4) & 3) << 4;   // range bases (x16)
  const int e1 = ((ob >> 2) & 3) << 4;
  const int e2 = (ob & 3) << 4;
  const int tid = threadIdx.x;
  const int rho = tid >> 4, sig = tid & 15;

  // ---- build monomial table from w (8 entries/thread) ----
  // P(x) = a3 x^3 + a2 x^2 + a1 x + a0 over nodes {-1,-1/3,1/3,1}
  #pragma unroll
  for (int kk = 0; kk < 8; ++kk) {
    const int r = tid + (kk << 8);
    const int c = r >> 5, i = r & 31;
    const float* wr = w + c * WW + 3 * i;
    const float v0 = wr[0] * (-9.0f / 16.0f);
    const float v1 = wr[1] * (27.0f / 16.0f);
    const float v2 = wr[2] * (-27.0f / 16.0f);
    const float v3 = wr[3] * (9.0f / 16.0f);
    const float a3 = v0 + v1 + v2 + v3;
    const float a2 = -v0 - v1 * (1.0f / 3.0f) + v2 * (1.0f / 3.0f) + v3;
    const float a1 = -v0 * (1.0f / 9.0f) - v1 - v2 - v3 * (1.0f / 9.0f);
    const float a0 =  v0 * (1.0f / 9.0f) + v1 * (1.0f / 3.0f)
                    - v2 * (1.0f / 3.0f) - v3 * (1.0f / 9.0f);
    h16x4 h;
    h[0] = (_Float16)a0; h[1] = (_Float16)a1;
    h[2] = (_Float16)a2; h[3] = (_Float16)a3;
    wexp[r] = h;
  }

  // ---- phase 1: load regions (own values -> regs, ids -> LDS) ----
  // region r: rows e[r], tiles e[(r+1)%3], offs e[(r+2)%3]
  float vals[3][16];
  #pragma unroll
  for (int r = 0; r < 3; ++r) {
    if (r < nreg) {
      const int rowb = (r == 0) ? e0 : (r == 1) ? e1 : e2;
      const int tilb = (r == 0) ? e1 : (r == 1) ? e2 : e0;
      const int offb = (r == 0) ? e2 : (r == 1) ? e0 : e1;
      const float* p = x + (((size_t)(b * NCH + rowb + rho)) << 12)
                         + ((tilb + sig) << 6) + offb;
      u32 pk[4];
      #pragma unroll
      for (int m = 0; m < 4; ++m) {
        const f32x4 q = *reinterpret_cast<const f32x4*>(p + (m << 2));
        u32 pw = 0;
        #pragma unroll
        for (int i = 0; i < 4; ++i) {
          const float vv = q[i];
          vals[r][m * 4 + i] = vv;
          const float tt = fmaf(vv, 16.0f, 16.0f);   // == (x+1)/2*32 bitwise
          int id = (int)tt;                           // trunc toward zero
          id = id < 0 ? 0 : (id > 31 ? 31 : id);
          pw |= (u32)id << (8 * i);
        }
        pk[m] = pw;
      }
      u32x4v pv; pv[0] = pk[0]; pv[1] = pk[1]; pv[2] = pk[2]; pv[3] = pk[3];
      *reinterpret_cast<u32x4v*>(&sid[r][rho * 272 + sig * 16]) = pv;
    }
  }
  __syncthreads();

  // ---- phase 2: cube n: c in e[n], t in e[(n+1)%3], u in e[(n+2)%3];
  //      own = vals[n]; ids from region (n+1)%nreg at [sig][k][rho] ----
  #pragma unroll
  for (int n = 0; n < 3; ++n) {
    if (n < nreg) {
      const int cb = (n == 0) ? e0 : (n == 1) ? e1 : e2;
      const int tb = (n == 0) ? e1 : (n == 1) ? e2 : e0;
      const int ub = (n == 0) ? e2 : (n == 1) ? e0 : e1;
      const int m  = (nreg == 1) ? 0 : (n + 1) % 3;
      const int c  = cb + rho;
      const int t  = tb + sig;
      const u32* sp = reinterpret_cast<const u32*>(
          &sid[m][sig * 272 + (rho & ~3)]);
      const int sh = (rho & 3) * 8;
      const int cw = c << 5;
      float* op = out + (((size_t)(b * NCH + c)) << 12) + (t << 6) + ub;

      #pragma unroll
      for (int m4 = 0; m4 < 4; ++m4) {
        f32x4 res;
        #pragma unroll
        for (int i = 0; i < 4; ++i) {
          const int k = m4 * 4 + i;
          const float xv = vals[n][k];
          const float tt = fmaf(xv, 16.0f, 16.0f);
          int idm = (int)tt;
          idm = idm < 0 ? 0 : (idm > 31 ? 31 : idm);
          const float xin = fmaf(xv, 32.0f, fmaf((float)idm, -2.0f, 31.0f));

          const int idw = (sp[k << 2] >> sh) & 31;    // byte (dword-broadcast read)
          const h16x4 hc = wexp[cw + idw];
          res[i] = fmaf(fmaf(fmaf((float)hc[3], xin, (float)hc[2]), xin,
                             (float)hc[1]), xin, (float)hc[0]);
        }
        *reinterpret_cast<f32x4*>(op + (m4 << 2)) = res;
      }
    }
  }
}

extern "C" void kernel_launch(void* const* d_in, const int* in_sizes, int n_in,
                              void* d_out, int out_size, void* d_ws, size_t ws_size,
                              hipStream_t stream) {
  const float* x = (const float*)d_in[0];
  const float* w = (const float*)d_in[1];
  float* out    = (float*)d_out;
  pw_kernel<<<dim3(24, 32), 256, 0, stream>>>(x, w, out);
}

// Round 10
// 16.382 us; speedup vs baseline: 1.6451x; 1.6451x over previous
//
#include <hip/hip_runtime.h>

#define NCH      64
#define WW       97
#define NTHREADS 512

typedef float        f32x4 __attribute__((ext_vector_type(4)));
typedef _Float16     h16x4 __attribute__((ext_vector_type(4)));
typedef unsigned int u32;
typedef unsigned int u32x2 __attribute__((ext_vector_type(2)));

// Fused kernel: batch-per-XCD swizzle + coalesced row staging through LDS.
// Output (c, t, u): own value x[b][c][64t+u]; weight-window id from the bin of
// x[b][t][64u+c] (transposed source). WG(b,t) stages row t's 4096 bin-ids in
// LDS via a fully-coalesced read; swizzle keeps batch b's slab in one XCD L2
// so the row re-read dedups against own-reads of sibling WGs.
__global__ __launch_bounds__(NTHREADS)
void pw_kernel(const float* __restrict__ x,
               const float* __restrict__ w,
               float* __restrict__ out) {
  __shared__ h16x4 wexp[NCH * 32];                       // 16 KB monomial f16 coeffs
  __shared__ __align__(8) unsigned char sidT[64 * 72];   // ids[u][c], row stride 72

  const int g   = blockIdx.x;
  const int b   = (g & 7) | ((g >> 9) << 3);   // XCD = g%8 = b%8
  const int t   = (g >> 3) & 63;
  const int tid = threadIdx.x;

  // ---- row read (issued first; fully coalesced: 32 B/thread) ----
  const float* xrow = x + (((size_t)(b * NCH + t)) << 12);
  const f32x4 r0 = *reinterpret_cast<const f32x4*>(xrow + (tid << 3));
  const f32x4 r1 = *reinterpret_cast<const f32x4*>(xrow + (tid << 3) + 4);

  // ---- build monomial table from w (4 entries/thread; w is L2-hot) ----
  #pragma unroll
  for (int k = 0; k < 4; ++k) {
    const int r = tid + k * NTHREADS;   // [0, 2048)
    const int c = r >> 5, i = r & 31;
    const float* wr = w + c * WW + 3 * i;
    const float v0 = wr[0] * (-9.0f / 16.0f);
    const float v1 = wr[1] * (27.0f / 16.0f);
    const float v2 = wr[2] * (-27.0f / 16.0f);
    const float v3 = wr[3] * (9.0f / 16.0f);
    h16x4 h;
    h[3] = (_Float16)(v0 + v1 + v2 + v3);
    h[2] = (_Float16)(-v0 - v1 * (1.0f / 3.0f) + v2 * (1.0f / 3.0f) + v3);
    h[1] = (_Float16)(-v0 * (1.0f / 9.0f) - v1 - v2 - v3 * (1.0f / 9.0f));
    h[0] = (_Float16)( v0 * (1.0f / 9.0f) + v1 * (1.0f / 3.0f)
                     - v2 * (1.0f / 3.0f) - v3 * (1.0f / 9.0f));
    wexp[r] = h;
  }

  // ---- pack 8 ids -> one ds_write_b64 ----
  // thread s owns row elems 8s..8s+7: u = s>>3, c = 8(s&7)+i
  {
    u32 p0 = 0, p1 = 0;
    #pragma unroll
    for (int i = 0; i < 4; ++i) {
      const float t0 = fmaf(r0[i], 16.0f, 16.0f);   // == (x+1)/2*32 bitwise
      int id0 = (int)t0;                             // trunc toward zero
      id0 = id0 < 0 ? 0 : (id0 > 31 ? 31 : id0);
      p0 |= (u32)id0 << (8 * i);
      const float t1 = fmaf(r1[i], 16.0f, 16.0f);
      int id1 = (int)t1;
      id1 = id1 < 0 ? 0 : (id1 > 31 ? 31 : id1);
      p1 |= (u32)id1 << (8 * i);
    }
    u32x2 pv; pv[0] = p0; pv[1] = p1;
    *reinterpret_cast<u32x2*>(&sidT[(tid >> 3) * 72 + ((tid & 7) << 3)]) = pv;
  }
  __syncthreads();

  // ---- main body: thread owns c-pair x u-quad (8 outputs) ----
  const int l  = tid & 63;
  const int wv = tid >> 6;            // 0..7
  const int q  = l & 15;              // u-quad index
  const int a  = l >> 4;              // 0..3
  const int u0 = q << 2;
  const int c0 = (wv << 3) + (a << 1);   // even channel pair start

  // 4 id dwords: sidT[u0+i][c0&~3 .. +3]
  const int dwo = (c0 >> 2) << 2;     // dword-aligned byte offset within row
  u32 idw[4];
  #pragma unroll
  for (int i = 0; i < 4; ++i)
    idw[i] = *reinterpret_cast<const u32*>(&sidT[(u0 + i) * 72 + dwo]);
  const int sh0 = (c0 & 3) * 8;

  const size_t obase = (((size_t)(b * NCH + c0)) << 12) + ((size_t)(t << 6)) + u0;

  #pragma unroll
  for (int j = 0; j < 2; ++j) {
    const f32x4 own = *reinterpret_cast<const f32x4*>(x + obase + ((size_t)j << 12));
    const int cb = (c0 + j) << 5;
    const int sh = sh0 + 8 * j;
    f32x4 res;
    #pragma unroll
    for (int i = 0; i < 4; ++i) {
      // own bin id -> local coordinate (ids bitwise-identical to reference)
      const float xv = own[i];
      const float tt = fmaf(xv, 16.0f, 16.0f);
      int idm = (int)tt;
      idm = idm < 0 ? 0 : (idm > 31 ? 31 : idm);
      const float xin = fmaf(xv, 32.0f, fmaf((float)idm, -2.0f, 31.0f));

      // transposed id -> coefficient window (ds_read_b64)
      const int widx = (idw[i] >> sh) & 31;
      const h16x4 hc = wexp[cb + widx];
      res[i] = fmaf(fmaf(fmaf((float)hc[3], xin, (float)hc[2]), xin,
                         (float)hc[1]), xin, (float)hc[0]);
    }
    __builtin_nontemporal_store(res,
        reinterpret_cast<f32x4*>(out + obase + ((size_t)j << 12)));
  }
}

extern "C" void kernel_launch(void* const* d_in, const int* in_sizes, int n_in,
                              void* d_out, int out_size, void* d_ws, size_t ws_size,
                              hipStream_t stream) {
  const float* x = (const float*)d_in[0];
  const float* w = (const float*)d_in[1];
  float* out    = (float*)d_out;
  pw_kernel<<<dim3(2048), NTHREADS, 0, stream>>>(x, w, out);
}